// Round 12
// baseline (140.190 us; speedup 1.0000x reference)
//
#include <hip/hip_runtime.h>

#define D_DIM    1024
#define PER_LANE 16   // D / 64
#define NLAYER   2
#define NPAIR    8    // ent pairs per lane
#define WPB      4    // waves per block (blockDim = 256)
#define ROWS_PW  8    // rows per wave

// Native 4-float vector for nontemporal builtins (HIP float4 class rejected).
typedef float nf4 __attribute__((ext_vector_type(4)));

// XOR swizzle over 16B chunk index: bijective involution; makes the coalesced
// phase (chunks q*64+l) and the segment phase (chunks 4l+r) bank-uniform.
__device__ __forceinline__ int swz(int c) { return c ^ ((c >> 3) & 7); }

// DPP move with explicit old-value for invalid/masked lanes.
// Empirical convention (validated R6): row_shr:d  => lane i <- lane i-d.
// Hence wave_shr:1 (0x138) = shfl_up(1); wave_shl:1 (0x130) = shfl_down(1).
template<int CTRL, int RMASK>
__device__ __forceinline__ float dpp_mov(float src, float oldv) {
    return __int_as_float(__builtin_amdgcn_update_dpp(
        __float_as_int(oldv), __float_as_int(src), CTRL, RMASK, 0xF, false));
}

// ---------------- kernel 1: angle tables (once per call) ----------------
// tab floats: [0]=cos_local[2][1024], [2048]=sin_local[2][1024],
//             [4096]=cos_ent[2][512], [5120]=sin_ent[2][512]
__global__ void angles_kernel(const float* __restrict__ la,
                              const float* __restrict__ ea,
                              float* __restrict__ tab) {
    int t  = blockIdx.x * blockDim.x + threadIdx.x;
    int nt = gridDim.x * blockDim.x;
    for (int i = t; i < NLAYER * D_DIM; i += nt) {
        float s, c; sincosf(la[i], &s, &c);
        tab[i] = c; tab[2048 + i] = s;
    }
    for (int i = t; i < NLAYER * (D_DIM / 2); i += nt) {
        float s, c; sincosf(ea[i], &s, &c);
        tab[4096 + i] = c; tab[5120 + i] = s;
    }
}

// ---------------- kernel 2: main ----------------
// No DMA, no inline-asm waits: pure reg staging with pinned issue-early
// loads (sched_barrier) and write-late; single reused 4KB buffer per wave;
// launch_bounds caps VGPR at 128 so 4 blocks/CU (16 waves) are resident.
__global__ __launch_bounds__(256, 4) void qent_kernel(
        const float* __restrict__ x,
        const float* __restrict__ tab,
        float* __restrict__ out, int B)
{
    const int lane  = threadIdx.x & 63;
    const int wid   = threadIdx.x >> 6;
    const int gwave = blockIdx.x * WPB + wid;

    __shared__ float4 tb[WPB][256];                // 16 KB: shared transpose
    __shared__ float2 lds_ces[NLAYER][NPAIR][64];  // 8 KB: {cos,sin} packed

    // Ent coefficients -> LDS [L][m][lane] (lane-consecutive, conflict-free).
    for (int t = threadIdx.x; t < NLAYER * 512; t += 256) {
        int L = t >> 9, p = t & 511;
        int m = p >> 6, ln = p & 63;
        float2 cs;
        cs.x = tab[4096 + L * 512 + ln * 8 + m];
        cs.y = tab[5120 + L * 512 + ln * 8 + m];
        lds_ces[L][m][ln] = cs;
    }
    __syncthreads();

    // Local-rotation coefficients in registers (coalesced float4 loads).
    float cl[NLAYER][PER_LANE], sl[NLAYER][PER_LANE];
    #pragma unroll
    for (int L = 0; L < NLAYER; ++L) {
        const float4* cp = reinterpret_cast<const float4*>(tab + L * D_DIM + lane * PER_LANE);
        const float4* sp = reinterpret_cast<const float4*>(tab + 2048 + L * D_DIM + lane * PER_LANE);
        #pragma unroll
        for (int q = 0; q < 4; ++q) {
            float4 c4 = cp[q], s4 = sp[q];
            cl[L][4*q+0] = c4.x; cl[L][4*q+1] = c4.y; cl[L][4*q+2] = c4.z; cl[L][4*q+3] = c4.w;
            sl[L][4*q+0] = s4.x; sl[L][4*q+1] = s4.y; sl[L][4*q+2] = s4.z; sl[L][4*q+3] = s4.w;
        }
    }

    const int row0 = gwave * ROWS_PW;

    // Prologue: row0 -> tb (coalesced load, swizzled LDS image).
    {
        const float4* rp = reinterpret_cast<const float4*>(x + (size_t)row0 * D_DIM);
        #pragma unroll
        for (int q = 0; q < 4; ++q) tb[wid][swz(q * 64 + lane)] = rp[q * 64 + lane];
    }

    for (int it = 0; it < ROWS_PW; ++it) {
        // (a) ISSUE-EARLY: next row's 4 coalesced loads into registers,
        // pinned here by a full scheduling barrier so they cannot sink.
        float4 nxt[4];
        if (it + 1 < ROWS_PW) {
            const float4* rp =
                reinterpret_cast<const float4*>(x + (size_t)(row0 + it + 1) * D_DIM);
            #pragma unroll
            for (int q = 0; q < 4; ++q) nxt[q] = rp[q * 64 + lane];
        }
        __builtin_amdgcn_sched_barrier(0);

        // (b) segment read: lane l owns columns [16l, 16l+16).
        float v[PER_LANE];
        #pragma unroll
        for (int r = 0; r < 4; ++r) {
            float4 t = tb[wid][swz(4 * lane + r)];
            v[4*r+0] = t.x; v[4*r+1] = t.y; v[4*r+2] = t.z; v[4*r+3] = t.w;
        }

        // (c) compute (validated core, unchanged).
        #pragma unroll
        for (int L = 0; L < NLAYER; ++L) {
            // vnf = lane l+1's ORIGINAL v[0]  (shfl_down 1 == wave_shl:1)
            float vnf = dpp_mov<0x130, 0xF>(v[0], v[0]);

            // pass 1: this lane's composed affine map (A, B)
            float A = 1.f, Bv = 0.f;
            #pragma unroll
            for (int k = 0; k < PER_LANE; ++k) {
                float vn = (k < PER_LANE - 1) ? v[k + 1] : vnf;
                Bv = sl[L][k] * Bv + cl[L][k] * vn;
                A  = sl[L][k] * A;
            }

            // inclusive affine scan across 64 lanes, all-DPP (VALU pipe).
            float Ai = A, Bi = Bv;
            #define SCAN_STEP(CTRL, RMASK) do {                   \
                float Au = dpp_mov<CTRL, RMASK>(Ai, 1.0f);        \
                float Bu = dpp_mov<CTRL, RMASK>(Bi, 0.0f);        \
                Bi = fmaf(Ai, Bu, Bi);                            \
                Ai *= Au; } while (0)
            SCAN_STEP(0x111, 0xF);   // row_shr:1
            SCAN_STEP(0x112, 0xF);   // row_shr:2
            SCAN_STEP(0x114, 0xF);   // row_shr:4
            SCAN_STEP(0x118, 0xF);   // row_shr:8
            SCAN_STEP(0x142, 0xA);   // row_bcast:15 -> rows 1,3
            SCAN_STEP(0x143, 0xC);   // row_bcast:31 -> rows 2,3
            #undef SCAN_STEP

            // exclusive shift by one lane (shfl_up 1 == wave_shr:1)
            float Ax = dpp_mov<0x138, 0xF>(Ai, 0.0f);
            float Bx = dpp_mov<0x138, 0xF>(Bi, 0.0f);
            float v0b = __int_as_float(
                __builtin_amdgcn_readfirstlane(__float_as_int(v[0])));
            float u   = (lane == 0) ? v[0] : fmaf(Ax, v0b, Bx);

            // replay: finals f_i = c_i u_i - s_i v_{i+1}
            #pragma unroll
            for (int k = 0; k < PER_LANE - 1; ++k) {
                float vn = v[k + 1];
                float f  = cl[L][k] * u - sl[L][k] * vn;
                u        = sl[L][k] * u + cl[L][k] * vn;
                v[k] = f;
            }
            // wrap step i = D-1 uses a0 = provisional f_0 (lane 0)
            float a0 = __int_as_float(
                __builtin_amdgcn_readfirstlane(__float_as_int(v[0])));
            float vn15 = (lane == 63) ? a0 : vnf;
            float f15  = cl[L][PER_LANE-1] * u - sl[L][PER_LANE-1] * vn15;
            float un   = sl[L][PER_LANE-1] * u + cl[L][PER_LANE-1] * vn15;
            v[PER_LANE-1] = f15;
            float f0new = __int_as_float(
                __builtin_amdgcn_readlane(__float_as_int(un), 63));
            v[0] = (lane == 0) ? f0new : v[0];

            // ent layer: disjoint pairs, lane-local
            #pragma unroll
            for (int m = 0; m < NPAIR; ++m) {
                float2 cs = lds_ces[L][m][lane];
                float x0 = v[2*m], x1 = v[2*m+1];
                v[2*m]   = cs.x * x0 - cs.y * x1;
                v[2*m+1] = cs.y * x0 + cs.x * x1;
            }
        }

        // (d) output transpose into the SAME buffer (in-wave ds ordering
        // guarantees (b)'s reads completed), then coalesced nt-store.
        #pragma unroll
        for (int r = 0; r < 4; ++r) {
            float4 t;
            t.x = v[4*r+0]; t.y = v[4*r+1]; t.z = v[4*r+2]; t.w = v[4*r+3];
            tb[wid][swz(4 * lane + r)] = t;
        }
        nf4* op = reinterpret_cast<nf4*>(out + (size_t)(row0 + it) * D_DIM);
        #pragma unroll
        for (int q = 0; q < 4; ++q) {
            float4 t = tb[wid][swz(q * 64 + lane)];
            nf4 w; w.x = t.x; w.y = t.y; w.z = t.z; w.w = t.w;
            __builtin_nontemporal_store(w, &op[q * 64 + lane]);
        }

        // (e) WRITE-LATE: staged next row -> tb (after (d)'s reads; the
        // compiler's vmcnt wait for nxt lands here, ~3000 cyc after issue).
        if (it + 1 < ROWS_PW) {
            #pragma unroll
            for (int q = 0; q < 4; ++q) tb[wid][swz(q * 64 + lane)] = nxt[q];
        }
    }
}

extern "C" void kernel_launch(void* const* d_in, const int* in_sizes, int n_in,
                              void* d_out, int out_size, void* d_ws, size_t ws_size,
                              hipStream_t stream) {
    const float* x  = (const float*)d_in[0];
    const float* la = (const float*)d_in[1];
    const float* ea = (const float*)d_in[2];
    float* out = (float*)d_out;
    float* tab = (float*)d_ws;               // 6144 floats = 24 KB
    int B = in_sizes[0] / D_DIM;             // 32768

    angles_kernel<<<64, 256, 0, stream>>>(la, ea, tab);
    // 1024 blocks x 4 waves x 8 rows/wave; 24KB LDS + <=128 VGPR
    // -> 4 blocks/CU, 16 waves/CU, all blocks co-resident.
    qent_kernel<<<1024, 256, 0, stream>>>(x, tab, out, B);
}

// Round 13
// 55.246 us; speedup vs baseline: 2.5376x; 2.5376x over previous
//
#include <hip/hip_runtime.h>

#define D_DIM    1024
#define PER_LANE 16   // D / 64
#define NLAYER   2
#define NPAIR    8    // ent pairs per lane
#define WPB      4    // waves per block (blockDim = 256)
#define NITER    8    // iterations per wave
#define ROWS_PI  2    // rows per iteration
#define ROWS_PW  (NITER * ROWS_PI)   // 16 rows per wave

// Native 4-float vector for nontemporal builtins (HIP float4 class rejected).
typedef float nf4 __attribute__((ext_vector_type(4)));

// XOR swizzle over 16B chunk index: bijective involution; makes the coalesced
// phase (chunks q*64+l) and the segment phase (chunks 4l+r) bank-uniform.
__device__ __forceinline__ int swz(int c) { return c ^ ((c >> 3) & 7); }

// DPP move with explicit old-value for invalid/masked lanes.
// Empirical convention (validated R6): row_shr:d  => lane i <- lane i-d.
// Hence wave_shr:1 (0x138) = shfl_up(1); wave_shl:1 (0x130) = shfl_down(1).
template<int CTRL, int RMASK>
__device__ __forceinline__ float dpp_mov(float src, float oldv) {
    return __int_as_float(__builtin_amdgcn_update_dpp(
        __float_as_int(oldv), __float_as_int(src), CTRL, RMASK, 0xF, false));
}

// ---------------- kernel 1: angle tables (once per call) ----------------
// tab floats: [0]=cos_local[2][1024], [2048]=sin_local[2][1024],
//             [4096]=cos_ent[2][512], [5120]=sin_ent[2][512]
__global__ void angles_kernel(const float* __restrict__ la,
                              const float* __restrict__ ea,
                              float* __restrict__ tab) {
    int t  = blockIdx.x * blockDim.x + threadIdx.x;
    int nt = gridDim.x * blockDim.x;
    for (int i = t; i < NLAYER * D_DIM; i += nt) {
        float s, c; sincosf(la[i], &s, &c);
        tab[i] = c; tab[2048 + i] = s;
    }
    for (int i = t; i < NLAYER * (D_DIM / 2); i += nt) {
        float s, c; sincosf(ea[i], &s, &c);
        tab[4096 + i] = c; tab[5120 + i] = s;
    }
}

// ---------------- kernel 2: main ----------------
__global__ __launch_bounds__(256) void qent_kernel(
        const float* __restrict__ x,
        const float* __restrict__ tab,
        float* __restrict__ out, int B)
{
    const int lane  = threadIdx.x & 63;
    const int wid   = threadIdx.x >> 6;
    const int gwave = blockIdx.x * WPB + wid;

    // 2 bufs x 2 rows x 256 chunks x 16B = 16 KB per wave -> 64 KB + 8 KB.
    __shared__ float4 tb[WPB][2][2 * 256];
    __shared__ float2 lds_ces[NLAYER][NPAIR][64];  // {cos,sin} packed

    // Ent coefficients -> LDS [L][m][lane] (lane-consecutive, conflict-free).
    for (int t = threadIdx.x; t < NLAYER * 512; t += 256) {
        int L = t >> 9, p = t & 511;
        int m = p >> 6, ln = p & 63;
        float2 cs;
        cs.x = tab[4096 + L * 512 + ln * 8 + m];
        cs.y = tab[5120 + L * 512 + ln * 8 + m];
        lds_ces[L][m][ln] = cs;
    }
    __syncthreads();

    // Local-rotation coefficients in registers (coalesced float4 loads).
    float cl[NLAYER][PER_LANE], sl[NLAYER][PER_LANE];
    #pragma unroll
    for (int L = 0; L < NLAYER; ++L) {
        const float4* cp = reinterpret_cast<const float4*>(tab + L * D_DIM + lane * PER_LANE);
        const float4* sp = reinterpret_cast<const float4*>(tab + 2048 + L * D_DIM + lane * PER_LANE);
        #pragma unroll
        for (int q = 0; q < 4; ++q) {
            float4 c4 = cp[q], s4 = sp[q];
            cl[L][4*q+0] = c4.x; cl[L][4*q+1] = c4.y; cl[L][4*q+2] = c4.z; cl[L][4*q+3] = c4.w;
            sl[L][4*q+0] = s4.x; sl[L][4*q+1] = s4.y; sl[L][4*q+2] = s4.z; sl[L][4*q+3] = s4.w;
        }
    }

    // Direct-to-LDS stage of TWO rows (8 DMA ops), pre-swizzled source so the
    // LDS image is swizzled (validated R5-R8 pattern).
    const int l2 = lane ^ (lane >> 3);
    auto stage2 = [&](int b, int row) {
        #pragma unroll
        for (int h = 0; h < ROWS_PI; ++h) {
            const float* src = x + (size_t)(row + h) * D_DIM;
            #pragma unroll
            for (int q = 0; q < 4; ++q) {
                __builtin_amdgcn_global_load_lds(
                    (const __attribute__((address_space(1))) void*)(src + q * 256 + l2 * 4),
                    (__attribute__((address_space(3))) void*)&tb[wid][b][h * 256 + q * 64],
                    16, 0, 0);
            }
        }
    };

    const int row0 = gwave * ROWS_PW;
    stage2(0, row0);

    for (int it = 0; it < NITER; ++it) {
        const int cur  = it & 1;
        const int rbase = row0 + it * ROWS_PI;

        // Issue next stage, then counted wait (8 ops per stage/store group):
        // steady queue = [stage(cur) 8][stores(prev) 8][stage(next) 8]
        //   -> vmcnt(16) retires exactly stage(cur).
        // it==0: [stage0 8][stage1 8] -> vmcnt(8).
        // it==NITER-1: [stage 8][stores 8] -> vmcnt(8).
        if (it + 1 < NITER) {
            stage2(cur ^ 1, rbase + ROWS_PI);
            if (it == 0) asm volatile("s_waitcnt vmcnt(8)"  ::: "memory");
            else         asm volatile("s_waitcnt vmcnt(16)" ::: "memory");
        } else {
            asm volatile("s_waitcnt vmcnt(8)" ::: "memory");
        }

        #pragma unroll
        for (int h = 0; h < ROWS_PI; ++h) {
            const int hb = h * 256;

            // ---- segment read: lane l owns columns [16l, 16l+16) ----
            float v[PER_LANE];
            #pragma unroll
            for (int r = 0; r < 4; ++r) {
                float4 t = tb[wid][cur][hb + swz(4 * lane + r)];
                v[4*r+0] = t.x; v[4*r+1] = t.y; v[4*r+2] = t.z; v[4*r+3] = t.w;
            }

            #pragma unroll
            for (int L = 0; L < NLAYER; ++L) {
                // ------- local chain: u_{i+1} = s_i u_i + c_i v_{i+1} -------
                // vnf = lane l+1's ORIGINAL v[0]  (shfl_down 1 == wave_shl:1)
                float vnf = dpp_mov<0x130, 0xF>(v[0], v[0]);

                // pass 1: this lane's composed affine map (A, B)
                float A = 1.f, Bv = 0.f;
                #pragma unroll
                for (int k = 0; k < PER_LANE; ++k) {
                    float vn = (k < PER_LANE - 1) ? v[k + 1] : vnf;
                    Bv = sl[L][k] * Bv + cl[L][k] * vn;
                    A  = sl[L][k] * A;
                }

                // inclusive affine scan across 64 lanes, all-DPP (VALU pipe).
                float Ai = A, Bi = Bv;
                #define SCAN_STEP(CTRL, RMASK) do {                   \
                    float Au = dpp_mov<CTRL, RMASK>(Ai, 1.0f);        \
                    float Bu = dpp_mov<CTRL, RMASK>(Bi, 0.0f);        \
                    Bi = fmaf(Ai, Bu, Bi);                            \
                    Ai *= Au; } while (0)
                SCAN_STEP(0x111, 0xF);   // row_shr:1
                SCAN_STEP(0x112, 0xF);   // row_shr:2
                SCAN_STEP(0x114, 0xF);   // row_shr:4
                SCAN_STEP(0x118, 0xF);   // row_shr:8
                SCAN_STEP(0x142, 0xA);   // row_bcast:15 -> rows 1,3
                SCAN_STEP(0x143, 0xC);   // row_bcast:31 -> rows 2,3
                #undef SCAN_STEP

                // exclusive shift by one lane (shfl_up 1 == wave_shr:1)
                float Ax = dpp_mov<0x138, 0xF>(Ai, 0.0f);
                float Bx = dpp_mov<0x138, 0xF>(Bi, 0.0f);
                float v0b = __int_as_float(
                    __builtin_amdgcn_readfirstlane(__float_as_int(v[0])));
                float u   = (lane == 0) ? v[0] : fmaf(Ax, v0b, Bx);

                // replay: finals f_i = c_i u_i - s_i v_{i+1}
                #pragma unroll
                for (int k = 0; k < PER_LANE - 1; ++k) {
                    float vn = v[k + 1];
                    float f  = cl[L][k] * u - sl[L][k] * vn;
                    u        = sl[L][k] * u + cl[L][k] * vn;
                    v[k] = f;
                }
                // wrap step i = D-1 uses a0 = provisional f_0 (lane 0)
                float a0 = __int_as_float(
                    __builtin_amdgcn_readfirstlane(__float_as_int(v[0])));
                float vn15 = (lane == 63) ? a0 : vnf;
                float f15  = cl[L][PER_LANE-1] * u - sl[L][PER_LANE-1] * vn15;
                float un   = sl[L][PER_LANE-1] * u + cl[L][PER_LANE-1] * vn15;
                v[PER_LANE-1] = f15;
                float f0new = __int_as_float(
                    __builtin_amdgcn_readlane(__float_as_int(un), 63));
                v[0] = (lane == 0) ? f0new : v[0];

                // ent layer: disjoint pairs, lane-local
                #pragma unroll
                for (int m = 0; m < NPAIR; ++m) {
                    float2 cs = lds_ces[L][m][lane];
                    float x0 = v[2*m], x1 = v[2*m+1];
                    v[2*m]   = cs.x * x0 - cs.y * x1;
                    v[2*m+1] = cs.y * x0 + cs.x * x1;
                }
            }

            // ---- segment write back (swizzled, same half-buffer), then
            //      coalesced nt-store ----
            #pragma unroll
            for (int r = 0; r < 4; ++r) {
                float4 t;
                t.x = v[4*r+0]; t.y = v[4*r+1]; t.z = v[4*r+2]; t.w = v[4*r+3];
                tb[wid][cur][hb + swz(4 * lane + r)] = t;
            }
            nf4* op = reinterpret_cast<nf4*>(out + (size_t)(rbase + h) * D_DIM);
            #pragma unroll
            for (int q = 0; q < 4; ++q) {
                float4 t = tb[wid][cur][hb + swz(q * 64 + lane)];
                nf4 w; w.x = t.x; w.y = t.y; w.z = t.z; w.w = t.w;
                __builtin_nontemporal_store(w, &op[q * 64 + lane]);
            }
        }
    }
}

extern "C" void kernel_launch(void* const* d_in, const int* in_sizes, int n_in,
                              void* d_out, int out_size, void* d_ws, size_t ws_size,
                              hipStream_t stream) {
    const float* x  = (const float*)d_in[0];
    const float* la = (const float*)d_in[1];
    const float* ea = (const float*)d_in[2];
    float* out = (float*)d_out;
    float* tab = (float*)d_ws;               // 6144 floats = 24 KB
    int B = in_sizes[0] / D_DIM;             // 32768

    angles_kernel<<<64, 256, 0, stream>>>(la, ea, tab);
    // 512 blocks x 4 waves x 16 rows/wave; 72 KB LDS -> 2 blocks/CU,
    // exactly co-resident (512 = 2x256), single round, no tail.
    qent_kernel<<<512, 256, 0, stream>>>(x, tab, out, B);
}

// Round 16
// 54.778 us; speedup vs baseline: 2.5592x; 1.0085x over previous
//
#include <hip/hip_runtime.h>

#define D_DIM    1024
#define PER_LANE 16   // D / 64
#define NLAYER   2
#define NPAIR    8    // ent pairs per lane
#define WPB      4    // waves per block (blockDim = 256)

// Native vector for buffer-store payload.
typedef unsigned int u4 __attribute__((ext_vector_type(4)));

// XOR swizzle over 16B chunk index: bijective involution; makes the coalesced
// phase (chunks q*64+l) and the segment phase (chunks 4l+r) bank-uniform.
__device__ __forceinline__ int swz(int c) { return c ^ ((c >> 3) & 7); }

// DPP move with explicit old-value for invalid/masked lanes.
// Empirical convention (validated R6): row_shr:d  => lane i <- lane i-d.
// Hence wave_shr:1 (0x138) = shfl_up(1); wave_shl:1 (0x130) = shfl_down(1).
template<int CTRL, int RMASK>
__device__ __forceinline__ float dpp_mov(float src, float oldv) {
    return __int_as_float(__builtin_amdgcn_update_dpp(
        __float_as_int(oldv), __float_as_int(src), CTRL, RMASK, 0xF, false));
}

// ---------------- kernel 1: angle tables (once per call) ----------------
// tab floats: [0]=cos_local[2][1024], [2048]=sin_local[2][1024],
//             [4096]=cos_ent[2][512], [5120]=sin_ent[2][512]
__global__ void angles_kernel(const float* __restrict__ la,
                              const float* __restrict__ ea,
                              float* __restrict__ tab) {
    int t  = blockIdx.x * blockDim.x + threadIdx.x;
    int nt = gridDim.x * blockDim.x;
    for (int i = t; i < NLAYER * D_DIM; i += nt) {
        float s, c; sincosf(la[i], &s, &c);
        tab[i] = c; tab[2048 + i] = s;
    }
    for (int i = t; i < NLAYER * (D_DIM / 2); i += nt) {
        float s, c; sincosf(ea[i], &s, &c);
        tab[4096 + i] = c; tab[5120 + i] = s;
    }
}

// ---------------- kernel 2: main ----------------
__global__ __launch_bounds__(256) void qent_kernel(
        const float* __restrict__ x,
        const float* __restrict__ tab,
        float* __restrict__ out, int B, int out_bytes)
{
    const int lane  = threadIdx.x & 63;
    const int wid   = threadIdx.x >> 6;
    const int gwave = blockIdx.x * WPB + wid;
    const int nwave = gridDim.x * WPB;

    __shared__ float4 tb[WPB][2][256];             // 32 KB: per-wave dbuf
    __shared__ float2 lds_ces[NLAYER][NPAIR][64];  // 8 KB: {cos,sin} packed

    // Ent coefficients -> LDS [L][m][lane] (lane-consecutive, conflict-free).
    for (int t = threadIdx.x; t < NLAYER * 512; t += 256) {
        int L = t >> 9, p = t & 511;
        int m = p >> 6, ln = p & 63;
        float2 cs;
        cs.x = tab[4096 + L * 512 + ln * 8 + m];
        cs.y = tab[5120 + L * 512 + ln * 8 + m];
        lds_ces[L][m][ln] = cs;
    }
    __syncthreads();

    // Local-rotation coefficients in registers (coalesced float4 loads).
    float cl[NLAYER][PER_LANE], sl[NLAYER][PER_LANE];
    #pragma unroll
    for (int L = 0; L < NLAYER; ++L) {
        const float4* cp = reinterpret_cast<const float4*>(tab + L * D_DIM + lane * PER_LANE);
        const float4* sp = reinterpret_cast<const float4*>(tab + 2048 + L * D_DIM + lane * PER_LANE);
        #pragma unroll
        for (int q = 0; q < 4; ++q) {
            float4 c4 = cp[q], s4 = sp[q];
            cl[L][4*q+0] = c4.x; cl[L][4*q+1] = c4.y; cl[L][4*q+2] = c4.z; cl[L][4*q+3] = c4.w;
            sl[L][4*q+0] = s4.x; sl[L][4*q+1] = s4.y; sl[L][4*q+2] = s4.z; sl[L][4*q+3] = s4.w;
        }
    }

    // Opaque SRD for the whole output buffer (stride=0 -> num_records bytes).
    __amdgpu_buffer_rsrc_t rsrc =
        __builtin_amdgcn_make_buffer_rsrc((void*)out, (short)0, out_bytes,
                                          0x00020000);

    // Direct-to-LDS stage, pre-swizzled global source: LDS chunk q*64+l
    // receives global chunk q*64 + (l ^ (l>>3))  =>  LDS image is swz'd.
    const int l2 = lane ^ (lane >> 3);
    auto stage = [&](int b, int row) {
        const float* src = x + (size_t)row * D_DIM;
        #pragma unroll
        for (int q = 0; q < 4; ++q) {
            __builtin_amdgcn_global_load_lds(
                (const __attribute__((address_space(1))) void*)(src + q * 256 + l2 * 4),
                (__attribute__((address_space(3))) void*)&tb[wid][b][q * 64],
                16, 0, 0);
        }
    };

    stage(0, gwave);

    int it = 0;
    for (int row = gwave; row < B; row += nwave, ++it) {
        const int cur  = it & 1;
        const int nrow = row + nwave;

        // Counted prefetch wait. Steady state outstanding at this point:
        // [stage(cur) 4][stores(prev row) 4][stage(next) 4] -> vmcnt(8)
        // retires exactly stage(cur), leaves stores+next in flight.
        if (nrow < B) {
            stage(cur ^ 1, nrow);
            if (it == 0) asm volatile("s_waitcnt vmcnt(4)" ::: "memory");
            else         asm volatile("s_waitcnt vmcnt(8)" ::: "memory");
        } else {
            asm volatile("s_waitcnt vmcnt(0)" ::: "memory");
        }

        // ---- segment read: lane l owns columns [16l, 16l+16) ----
        float v[PER_LANE];
        #pragma unroll
        for (int r = 0; r < 4; ++r) {
            float4 t = tb[wid][cur][swz(4 * lane + r)];
            v[4*r+0] = t.x; v[4*r+1] = t.y; v[4*r+2] = t.z; v[4*r+3] = t.w;
        }

        #pragma unroll
        for (int L = 0; L < NLAYER; ++L) {
            // ---------- local chain: u_{i+1} = s_i u_i + c_i v_{i+1} ----------
            // vnf = lane l+1's ORIGINAL v[0]  (shfl_down 1 == wave_shl:1)
            float vnf = dpp_mov<0x130, 0xF>(v[0], v[0]);

            // pass 1: this lane's composed affine map (A, B)
            float A = 1.f, Bv = 0.f;
            #pragma unroll
            for (int k = 0; k < PER_LANE; ++k) {
                float vn = (k < PER_LANE - 1) ? v[k + 1] : vnf;
                Bv = sl[L][k] * Bv + cl[L][k] * vn;
                A  = sl[L][k] * A;
            }

            // inclusive affine scan across 64 lanes, all-DPP (VALU pipe).
            float Ai = A, Bi = Bv;
            #define SCAN_STEP(CTRL, RMASK) do {                   \
                float Au = dpp_mov<CTRL, RMASK>(Ai, 1.0f);        \
                float Bu = dpp_mov<CTRL, RMASK>(Bi, 0.0f);        \
                Bi = fmaf(Ai, Bu, Bi);                            \
                Ai *= Au; } while (0)
            SCAN_STEP(0x111, 0xF);   // row_shr:1
            SCAN_STEP(0x112, 0xF);   // row_shr:2
            SCAN_STEP(0x114, 0xF);   // row_shr:4
            SCAN_STEP(0x118, 0xF);   // row_shr:8
            SCAN_STEP(0x142, 0xA);   // row_bcast:15 -> rows 1,3
            SCAN_STEP(0x143, 0xC);   // row_bcast:31 -> rows 2,3
            #undef SCAN_STEP

            // exclusive shift by one lane (shfl_up 1 == wave_shr:1)
            float Ax = dpp_mov<0x138, 0xF>(Ai, 0.0f);
            float Bx = dpp_mov<0x138, 0xF>(Bi, 0.0f);
            float v0b = __int_as_float(
                __builtin_amdgcn_readfirstlane(__float_as_int(v[0])));
            float u   = (lane == 0) ? v[0] : fmaf(Ax, v0b, Bx);

            // replay: finals f_i = c_i u_i - s_i v_{i+1}
            #pragma unroll
            for (int k = 0; k < PER_LANE - 1; ++k) {
                float vn = v[k + 1];
                float f  = cl[L][k] * u - sl[L][k] * vn;
                u        = sl[L][k] * u + cl[L][k] * vn;
                v[k] = f;
            }
            // wrap step i = D-1 uses a0 = provisional f_0 (lane 0)
            float a0 = __int_as_float(
                __builtin_amdgcn_readfirstlane(__float_as_int(v[0])));
            float vn15 = (lane == 63) ? a0 : vnf;
            float f15  = cl[L][PER_LANE-1] * u - sl[L][PER_LANE-1] * vn15;
            float un   = sl[L][PER_LANE-1] * u + cl[L][PER_LANE-1] * vn15;
            v[PER_LANE-1] = f15;
            float f0new = __int_as_float(
                __builtin_amdgcn_readlane(__float_as_int(un), 63));
            v[0] = (lane == 0) ? f0new : v[0];

            // ---------- ent layer: disjoint pairs, lane-local ----------
            #pragma unroll
            for (int m = 0; m < NPAIR; ++m) {
                float2 cs = lds_ces[L][m][lane];
                float x0 = v[2*m], x1 = v[2*m+1];
                v[2*m]   = cs.x * x0 - cs.y * x1;
                v[2*m+1] = cs.y * x0 + cs.x * x1;
            }
        }

        // ---- segment write back (swizzled), then coalesced streaming store:
        //      buffer_store_b128 with CPol = SC1|NT (aux=18) -> no LLC
        //      allocation, so the 134 MB input stays L3-resident.
        #pragma unroll
        for (int r = 0; r < 4; ++r) {
            float4 t;
            t.x = v[4*r+0]; t.y = v[4*r+1]; t.z = v[4*r+2]; t.w = v[4*r+3];
            tb[wid][cur][swz(4 * lane + r)] = t;
        }
        const int rowb = row * (D_DIM * 4);
        #pragma unroll
        for (int q = 0; q < 4; ++q) {
            float4 t = tb[wid][cur][swz(q * 64 + lane)];
            u4 w;
            w.x = __float_as_uint(t.x); w.y = __float_as_uint(t.y);
            w.z = __float_as_uint(t.z); w.w = __float_as_uint(t.w);
            int vo = rowb + q * 1024 + lane * 16;
            __builtin_amdgcn_raw_buffer_store_b128(w, rsrc, vo, 0, 18);
        }
    }
}

extern "C" void kernel_launch(void* const* d_in, const int* in_sizes, int n_in,
                              void* d_out, int out_size, void* d_ws, size_t ws_size,
                              hipStream_t stream) {
    const float* x  = (const float*)d_in[0];
    const float* la = (const float*)d_in[1];
    const float* ea = (const float*)d_in[2];
    float* out = (float*)d_out;
    float* tab = (float*)d_ws;               // 6144 floats = 24 KB
    int B = in_sizes[0] / D_DIM;             // 32768

    angles_kernel<<<64, 256, 0, stream>>>(la, ea, tab);
    // 1024 blocks x 4 waves, 8 rows/wave: 7/8 iterations fully prefetched.
    qent_kernel<<<1024, 256, 0, stream>>>(x, tab, out, B, out_size * 4);
}